// Round 24
// baseline (373.745 us; speedup 1.0000x reference)
//
#include <hip/hip_runtime.h>
#include <hip/hip_bf16.h>
#include <math.h>

typedef short bf16x8 __attribute__((ext_vector_type(8)));
typedef float f32x4 __attribute__((ext_vector_type(4)));
typedef float f32x2 __attribute__((ext_vector_type(2)));

__device__ __forceinline__ unsigned short f2bfu(float f) {
    __hip_bfloat16 h = __float2bfloat16(f);
    return __builtin_bit_cast(unsigned short, h);
}

__device__ __forceinline__ float fexp2(float x) {
    float r;
    asm("v_exp_f32 %0, %1" : "=v"(r) : "v"(x));
    return r;
}

__device__ __forceinline__ unsigned cvtpk_bf16(float lo, float hi) {
    unsigned r;
    asm("v_cvt_pk_bf16_f32 %0, %1, %2" : "=v"(r) : "v"(lo), "v"(hi));
    return r;
}

__device__ __forceinline__ float max3f(float a, float b, float c) {
    float r;
    asm("v_max3_f32 %0, %1, %2, %3" : "=v"(r) : "v"(a), "v"(b), "v"(c));
    return r;
}

__device__ __forceinline__ f32x2 pk_sub2(f32x2 a, f32x2 b) {
    f32x2 r;
    asm("v_pk_add_f32 %0, %1, %2 neg_lo:[0,1] neg_hi:[0,1]" : "=v"(r) : "v"(a), "v"(b));
    return r;
}

__device__ __forceinline__ f32x2 pk_add2(f32x2 a, f32x2 b) {
    f32x2 r;
    asm("v_pk_add_f32 %0, %1, %2" : "=v"(r) : "v"(a), "v"(b));
    return r;
}

__device__ __forceinline__ float gelu_fast(float x) {
    const float x2 = x * x;
    const float z = x * (0.7978845608f + 0.0356774081f * x2);
    const float e = fexp2(z * 2.88539008f);
    const float r = __builtin_amdgcn_rcpf(e + 1.0f);
    return x * (1.0f - r);
}

__device__ __forceinline__ void gload_lds16(const void* gsrc, void* ldst) {
    __builtin_amdgcn_global_load_lds((const __attribute__((address_space(1))) void*)gsrc,
                                     (__attribute__((address_space(3))) void*)ldst,
                                     16, 0, 0);
}

#define MFMA __builtin_amdgcn_mfma_f32_16x16x32_bf16
#define SBAR __builtin_amdgcn_s_barrier
#define SCHB __builtin_amdgcn_sched_barrier

// ---------------- fused f32 -> bf16 convert (all 7 tensors, one launch) ----------------
__global__ __launch_bounds__(256)
void cvt_all_kernel(const float4* __restrict__ x,  ushort4* __restrict__ xb,
                    const float4* __restrict__ wq, ushort4* __restrict__ wqb,
                    const float4* __restrict__ wk, ushort4* __restrict__ wkb,
                    const float4* __restrict__ wv, ushort4* __restrict__ wvb,
                    const float4* __restrict__ wo, ushort4* __restrict__ wob,
                    const float4* __restrict__ w1, ushort4* __restrict__ w1b,
                    const float4* __restrict__ w2, ushort4* __restrict__ w2b)
{
    const int i = blockIdx.x * 256 + threadIdx.x;
    const float4* src;
    ushort4* dst;
    int base;
    if (i < 2097152)      { src = x;  dst = xb;  base = 0; }
    else if (i < 2359296) { src = wq; dst = wqb; base = 2097152; }
    else if (i < 2621440) { src = wk; dst = wkb; base = 2359296; }
    else if (i < 2883584) { src = wv; dst = wvb; base = 2621440; }
    else if (i < 3145728) { src = wo; dst = wob; base = 2883584; }
    else if (i < 4194304) { src = w1; dst = w1b; base = 3145728; }
    else                  { src = w2; dst = w2b; base = 4194304; }
    const float4 v = src[i - base];
    ushort4 o;
    o.x = f2bfu(v.x); o.y = f2bfu(v.y); o.z = f2bfu(v.z); o.w = f2bfu(v.w);
    dst[i - base] = o;
}

enum { EPI_QKV = 0, EPI_RES_OB = 2, EPI_GELU = 3 };

// ======== 256x256 8-phase GEMM, 4Mx2N waves (proven R18 kernel, FFN1) ========
template<int EPI>
__global__ __launch_bounds__(512, 1)
void gemm8p(const __hip_bfloat16* __restrict__ A,
            const __hip_bfloat16* __restrict__ W,
            const float* __restrict__ bias,
            const void* __restrict__ resv,
            float scale,
            void* __restrict__ outp,
            int M, int N, int K)
{
    __shared__ __hip_bfloat16 As[2][256 * 64];
    __shared__ __hip_bfloat16 Bs[2][256 * 64];
    const int tid = threadIdx.x;
    const int lane = tid & 63;
    const int wid = tid >> 6;
    const int wr = wid >> 1;
    const int wc = wid & 1;
    const int g = lane >> 4, lr = lane & 15;
    const int row0 = blockIdx.x * 256;
    const int col0 = blockIdx.y * 256;

    f32x4 acc[4][8];
    const f32x4 zero = {0.f, 0.f, 0.f, 0.f};
#pragma unroll
    for (int m = 0; m < 4; ++m)
#pragma unroll
        for (int n = 0; n < 8; ++n) acc[m][n] = zero;

    const int arl = tid >> 3;
    const int agc = (tid & 7) ^ (arl & 7);
    const __hip_bfloat16* Abase = A + (size_t)(row0 + arl) * K + agc * 8;
    const __hip_bfloat16* Bbase = W + (size_t)(col0 + arl) * K + agc * 8;

    auto stageA = [&](int bi, int kt) {
#pragma unroll
        for (int q = 0; q < 4; ++q)
            gload_lds16(Abase + (size_t)(q * 64) * K + kt * 64,
                        (char*)As[bi] + q * 8192 + tid * 16);
    };
    auto stageB = [&](int bi, int h, int kt) {
#pragma unroll
        for (int j = 0; j < 2; ++j)
            gload_lds16(Bbase + (size_t)(h * 128 + j * 64) * K + kt * 64,
                        (char*)Bs[bi] + h * 16384 + j * 8192 + tid * 16);
    };

    const int NT = K >> 6;
    stageA(0, 0);
    stageB(0, 0, 0);
    stageB(0, 1, 0);
    stageA(1, 1);
    asm volatile("s_waitcnt vmcnt(4)" ::: "memory");
    SBAR();
    SCHB(0);

    const int swz = lr & 7;
    const int arow = wr * 64;
    const int brow = wc * 128;

    for (int t = 0; t < NT; ++t) {
        const int bi = t & 1;
        const __hip_bfloat16* Ab = As[bi];
        const __hip_bfloat16* Bb = Bs[bi];
        bf16x8 a[4], b0[4], b1[4];

#pragma unroll
        for (int m = 0; m < 4; ++m)
            a[m] = *(const bf16x8*)(Ab + (arow + m * 16 + lr) * 64 + ((g ^ swz) * 8));
#pragma unroll
        for (int n = 0; n < 4; ++n)
            b0[n] = *(const bf16x8*)(Bb + (brow + n * 16 + lr) * 64 + ((g ^ swz) * 8));
        if (t + 1 < NT) stageB(bi ^ 1, 0, t + 1);
        SCHB(0);
        SBAR();
        __builtin_amdgcn_s_setprio(1);
#pragma unroll
        for (int m = 0; m < 4; ++m)
#pragma unroll
            for (int n = 0; n < 4; ++n)
                acc[m][n] = MFMA(a[m], b0[n], acc[m][n], 0, 0, 0);
        __builtin_amdgcn_s_setprio(0);
        SBAR();

#pragma unroll
        for (int n = 0; n < 4; ++n)
            b1[n] = *(const bf16x8*)(Bb + (brow + (n + 4) * 16 + lr) * 64 + ((g ^ swz) * 8));
        if (t + 1 < NT) stageB(bi ^ 1, 1, t + 1);
        SCHB(0);
        SBAR();
        __builtin_amdgcn_s_setprio(1);
#pragma unroll
        for (int m = 0; m < 4; ++m)
#pragma unroll
            for (int n = 0; n < 4; ++n)
                acc[m][n + 4] = MFMA(a[m], b1[n], acc[m][n + 4], 0, 0, 0);
        __builtin_amdgcn_s_setprio(0);
        SBAR();

#pragma unroll
        for (int m = 0; m < 4; ++m)
            a[m] = *(const bf16x8*)(Ab + (arow + m * 16 + lr) * 64 + (((4 + g) ^ swz) * 8));
#pragma unroll
        for (int n = 0; n < 4; ++n)
            b0[n] = *(const bf16x8*)(Bb + (brow + n * 16 + lr) * 64 + (((4 + g) ^ swz) * 8));
        SCHB(0);
        SBAR();
        __builtin_amdgcn_s_setprio(1);
#pragma unroll
        for (int m = 0; m < 4; ++m)
#pragma unroll
            for (int n = 0; n < 4; ++n)
                acc[m][n] = MFMA(a[m], b0[n], acc[m][n], 0, 0, 0);
        __builtin_amdgcn_s_setprio(0);
        SBAR();

#pragma unroll
        for (int n = 0; n < 4; ++n)
            b1[n] = *(const bf16x8*)(Bb + (brow + (n + 4) * 16 + lr) * 64 + (((4 + g) ^ swz) * 8));
        if (t + 2 < NT) stageA(bi, t + 2);
        SCHB(0);
        SBAR();
        __builtin_amdgcn_s_setprio(1);
#pragma unroll
        for (int m = 0; m < 4; ++m)
#pragma unroll
            for (int n = 0; n < 4; ++n)
                acc[m][n + 4] = MFMA(a[m], b1[n], acc[m][n + 4], 0, 0, 0);
        __builtin_amdgcn_s_setprio(0);
        if (t + 1 < NT) {
            if (t + 2 < NT) asm volatile("s_waitcnt vmcnt(4)" ::: "memory");
            else            asm volatile("s_waitcnt vmcnt(0)" ::: "memory");
            SBAR();
            SCHB(0);
        }
    }

#pragma unroll
    for (int n = 0; n < 8; ++n) {
        const int cc = col0 + wc * 128 + n * 16 + lr;
        const float bv = bias[cc];
#pragma unroll
        for (int m = 0; m < 4; ++m) {
            const int rbase = row0 + wr * 64 + m * 16 + g * 4;
#pragma unroll
            for (int r = 0; r < 4; ++r) {
                const size_t idx = (size_t)(rbase + r) * N + cc;
                float v = acc[m][n][r] + bv;
                if (EPI == EPI_RES_OB) {
                    const float rv = __bfloat162float(((const __hip_bfloat16*)resv)[idx]);
                    ((__hip_bfloat16*)outp)[idx] = __float2bfloat16(v + rv);
                } else if (EPI == EPI_GELU) {
                    ((__hip_bfloat16*)outp)[idx] = __float2bfloat16(gelu_fast(v));
                }
            }
        }
    }
}

// ======== 128x256 2-phase 8-wave GEMM (FFN2: grid 64x4 = 256 blocks = 1/CU) ========
// 8 waves as 2Mx4N; wave owns 64x64 -> acc[4][4]. BK=64, NT=K/64.
// A: 3-buffer rotation As[t%3] (16KB each); B: 2-buffer Bs[t&1] (32KB each); 112KB LDS.
// Per K-tile: P1 {read a_ks0,b_ks0; stage B(t+1); bar; 16 MFMA; bar}
//             P2 {read a_ks1,b_ks1; stage A(t+2); bar; 16 MFMA; vmcnt(2); bar}
// Race audit: A(t+2)->As[(t+2)%3]=As[(t-1)%3], last read consumed before t-1's
// boundary barrier; B(t+1)->Bs[(t+1)&1]=Bs[(t-1)&1], same. FIFO: boundary
// vmcnt(2) leaves only A(t+2) in flight; B(t+1),A(t+1) proven landed.
template<int EPI>
__global__ __launch_bounds__(512, 1)
void gemm2p_w(const __hip_bfloat16* __restrict__ A,
              const __hip_bfloat16* __restrict__ W,
              const float* __restrict__ bias,
              const void* __restrict__ resv,
              void* __restrict__ outp,
              int M, int N, int K)
{
    __shared__ __hip_bfloat16 As[3][128 * 64];
    __shared__ __hip_bfloat16 Bs[2][256 * 64];
    const int tid = threadIdx.x;
    const int lane = tid & 63;
    const int wid = tid >> 6;
    const int wr = wid >> 2;          // 0..1 : 64-row band
    const int wc = wid & 3;           // 0..3 : 64-col band
    const int g = lane >> 4, lr = lane & 15;
    const int row0 = blockIdx.x * 128;
    const int col0 = blockIdx.y * 256;

    f32x4 acc[4][4];
    const f32x4 zero = {0.f, 0.f, 0.f, 0.f};
#pragma unroll
    for (int m = 0; m < 4; ++m)
#pragma unroll
        for (int n = 0; n < 4; ++n) acc[m][n] = zero;

    const int r0 = tid >> 3;                    // 0..63
    const int gc = (tid & 7) ^ (r0 & 7);        // pre-swizzled global chunk
    const __hip_bfloat16* Abase = A + (size_t)(row0 + r0) * K + gc * 8;
    const __hip_bfloat16* Bbase = W + (size_t)(col0 + r0) * K + gc * 8;

    auto stageA = [&](int bi, int kt) {         // 128 rows, 2 loads/thread
#pragma unroll
        for (int j = 0; j < 2; ++j)
            gload_lds16(Abase + (size_t)(j * 64) * K + kt * 64,
                        (char*)As[bi] + j * 8192 + tid * 16);
    };
    auto stageB = [&](int bi, int kt) {         // 256 rows, 4 loads/thread
#pragma unroll
        for (int j = 0; j < 4; ++j)
            gload_lds16(Bbase + (size_t)(j * 64) * K + kt * 64,
                        (char*)Bs[bi] + j * 8192 + tid * 16);
    };

    const int NT = K >> 6;
    // prologue: A(0), B(0), A(1); wait A0+B0 landed, A1 in flight
    stageA(0, 0);
    stageB(0, 0);
    stageA(1, 1);
    asm volatile("s_waitcnt vmcnt(2)" ::: "memory");
    SBAR();
    SCHB(0);

    const int swz = lr & 7;
    const int arow = wr * 64;
    const int brow = wc * 64;
    int a_cur = 0;

    for (int t = 0; t < NT; ++t) {
        const int bu = t & 1;
        const __hip_bfloat16* Ab = As[a_cur];
        const __hip_bfloat16* Bb = Bs[bu];
        const int a_nx2 = (a_cur == 0) ? 2 : a_cur - 1;   // (t+2)%3
        bf16x8 a[4], b[4];

        // ---- P1 (ks0): reads; stage B(t+1)
#pragma unroll
        for (int m = 0; m < 4; ++m)
            a[m] = *(const bf16x8*)(Ab + (arow + m * 16 + lr) * 64 + ((g ^ swz) * 8));
#pragma unroll
        for (int n = 0; n < 4; ++n)
            b[n] = *(const bf16x8*)(Bb + (brow + n * 16 + lr) * 64 + ((g ^ swz) * 8));
        if (t + 1 < NT) stageB(bu ^ 1, t + 1);
        SCHB(0);
        SBAR();
        __builtin_amdgcn_s_setprio(1);
#pragma unroll
        for (int m = 0; m < 4; ++m)
#pragma unroll
            for (int n = 0; n < 4; ++n)
                acc[m][n] = MFMA(a[m], b[n], acc[m][n], 0, 0, 0);
        __builtin_amdgcn_s_setprio(0);
        SBAR();

        // ---- P2 (ks1): reads; stage A(t+2)
#pragma unroll
        for (int m = 0; m < 4; ++m)
            a[m] = *(const bf16x8*)(Ab + (arow + m * 16 + lr) * 64 + (((4 + g) ^ swz) * 8));
#pragma unroll
        for (int n = 0; n < 4; ++n)
            b[n] = *(const bf16x8*)(Bb + (brow + n * 16 + lr) * 64 + (((4 + g) ^ swz) * 8));
        if (t + 2 < NT) stageA(a_nx2, t + 2);
        SCHB(0);
        SBAR();
        __builtin_amdgcn_s_setprio(1);
#pragma unroll
        for (int m = 0; m < 4; ++m)
#pragma unroll
            for (int n = 0; n < 4; ++n)
                acc[m][n] = MFMA(a[m], b[n], acc[m][n], 0, 0, 0);
        __builtin_amdgcn_s_setprio(0);
        if (t + 1 < NT) {
            if (t + 2 < NT) asm volatile("s_waitcnt vmcnt(2)" ::: "memory");
            else            asm volatile("s_waitcnt vmcnt(0)" ::: "memory");
            SBAR();
            SCHB(0);
        }
        a_cur = (a_cur == 2) ? 0 : a_cur + 1;
    }

    // ---- epilogue
#pragma unroll
    for (int n = 0; n < 4; ++n) {
        const int cc = col0 + wc * 64 + n * 16 + lr;
        const float bv = bias[cc];
#pragma unroll
        for (int m = 0; m < 4; ++m) {
            const int rbase = row0 + wr * 64 + m * 16 + g * 4;
#pragma unroll
            for (int r = 0; r < 4; ++r) {
                const size_t idx = (size_t)(rbase + r) * N + cc;
                float v = acc[m][n][r] + bv;
                if (EPI == EPI_RES_OB) {
                    const float rv = __bfloat162float(((const __hip_bfloat16*)resv)[idx]);
                    ((__hip_bfloat16*)outp)[idx] = __float2bfloat16(v + rv);
                } else if (EPI == EPI_GELU) {
                    ((__hip_bfloat16*)outp)[idx] = __float2bfloat16(gelu_fast(v));
                }
            }
        }
    }
}

// ---------------- BT GEMM (R6 config): 128x128, BK=32, 3-buffer counted vmcnt ----
template<int EPI>
__global__ __launch_bounds__(256, 3)
void gemm_bt(const __hip_bfloat16* __restrict__ A,
             const __hip_bfloat16* __restrict__ W,
             const float* __restrict__ bias,
             const void* __restrict__ resv,
             float scale,
             void* __restrict__ outp, void* __restrict__ outp2, void* __restrict__ outp3,
             int M, int N, int K)
{
    __shared__ __hip_bfloat16 As[3][128 * 32];
    __shared__ __hip_bfloat16 Ws[3][128 * 32];
    const int tid = threadIdx.x;
    const int lane = tid & 63;
    const int wid = tid >> 6;
    const int wr = wid >> 1, wc = wid & 1;
    const int g = lane >> 4, lr = lane & 15;
    const int row0 = blockIdx.x * 128;
    const int col0 = blockIdx.y * 128;

    f32x4 acc[4][4];
    const f32x4 zero = {0.f, 0.f, 0.f, 0.f};
#pragma unroll
    for (int m = 0; m < 4; ++m)
#pragma unroll
        for (int n = 0; n < 4; ++n) acc[m][n] = zero;

    const int c0 = tid, c1 = tid + 256;
    const int ar0 = c0 >> 2, ac0 = (c0 & 3) * 8;
    const int ar1 = c1 >> 2, ac1 = (c1 & 3) * 8;
    const __hip_bfloat16* Arow0 = A + (size_t)(row0 + ar0) * K + ac0;
    const __hip_bfloat16* Arow1 = A + (size_t)(row0 + ar1) * K + ac1;
    const __hip_bfloat16* Wrow0 = W + (size_t)(col0 + ar0) * K + ac0;
    const __hip_bfloat16* Wrow1 = W + (size_t)(col0 + ar1) * K + ac1;

    auto stage = [&](int bi, int k0) {
        gload_lds16(Arow0 + k0, (char*)As[bi] + c0 * 16);
        gload_lds16(Arow1 + k0, (char*)As[bi] + c1 * 16);
        gload_lds16(Wrow0 + k0, (char*)Ws[bi] + c0 * 16);
        gload_lds16(Wrow1 + k0, (char*)Ws[bi] + c1 * 16);
    };

    const int NT = K >> 5;
    stage(0, 0);
    stage(1, 32);
    asm volatile("s_waitcnt vmcnt(4)" ::: "memory");
    SBAR();
    SCHB(0);

    int cur = 0, stg = 2;
    int kpre = 64;
    for (int t = 0; t < NT; ++t) {
        if (t + 2 < NT) stage(stg, kpre);

        bf16x8 af[4], wf[4];
#pragma unroll
        for (int m = 0; m < 4; ++m)
            af[m] = *(const bf16x8*)(As[cur] + (wr * 64 + m * 16 + lr) * 32 + g * 8);
#pragma unroll
        for (int n = 0; n < 4; ++n)
            wf[n] = *(const bf16x8*)(Ws[cur] + (wc * 64 + n * 16 + lr) * 32 + g * 8);
#pragma unroll
        for (int m = 0; m < 4; ++m)
#pragma unroll
            for (int n = 0; n < 4; ++n)
                acc[m][n] = MFMA(af[m], wf[n], acc[m][n], 0, 0, 0);

        if (t + 1 < NT) {
            if (t + 2 < NT) asm volatile("s_waitcnt vmcnt(4)" ::: "memory");
            else            asm volatile("s_waitcnt vmcnt(0)" ::: "memory");
            SBAR();
            SCHB(0);
        }
        cur = (cur == 2) ? 0 : cur + 1;
        stg = (stg == 2) ? 0 : stg + 1;
        kpre += 32;
    }

#pragma unroll
    for (int n = 0; n < 4; ++n) {
        const int cc = col0 + wc * 64 + n * 16 + lr;
        const float bv = bias[cc];
#pragma unroll
        for (int m = 0; m < 4; ++m) {
            const int rbase = row0 + wr * 64 + m * 16 + g * 4;
            if (EPI == EPI_QKV) {
                const int seg = col0 >> 10;   // 0=Q, 1=K, 2=V (uniform per block)
                if (seg == 2) {
                    ushort4 u;
                    u.x = f2bfu(acc[m][n][0] + bv);
                    u.y = f2bfu(acc[m][n][1] + bv);
                    u.z = f2bfu(acc[m][n][2] + bv);
                    u.w = f2bfu(acc[m][n][3] + bv);
                    const int cc2 = cc - 2048;
                    const int h_ = cc2 >> 6, dh = cc2 & 63;
                    const int bb = rbase >> 11;
                    const int s = rbase & 2047;
                    *(ushort4*)((__hip_bfloat16*)outp3 +
                                (((size_t)bb * 16 + h_) * 64 + dh) * 2048 + s) = u;
                } else {
                    const float sc = (seg == 0) ? scale : 1.0f;
                    __hip_bfloat16* dst = (seg == 0) ? (__hip_bfloat16*)outp
                                                     : (__hip_bfloat16*)outp2;
                    const int ccl = cc & 1023;
#pragma unroll
                    for (int r = 0; r < 4; ++r)
                        dst[(size_t)(rbase + r) * 1024 + ccl] =
                            __float2bfloat16((acc[m][n][r] + bv) * sc);
                }
            } else {
#pragma unroll
                for (int r = 0; r < 4; ++r) {
                    const size_t idx = (size_t)(rbase + r) * N + cc;
                    float v = acc[m][n][r] + bv;
                    if (EPI == EPI_RES_OB) {
                        const float rv = __bfloat162float(((const __hip_bfloat16*)resv)[idx]);
                        ((__hip_bfloat16*)outp)[idx] = __float2bfloat16(v + rv);
                    } else if (EPI == EPI_GELU) {
                        ((__hip_bfloat16*)outp)[idx] = __float2bfloat16(gelu_fast(v));
                    }
                }
            }
        }
    }
}

// ---------------- Flash attention v3: 8 waves x 32 q-rows ----------------
__global__ __launch_bounds__(512, 4)
void attn_flash3(const __hip_bfloat16* __restrict__ Q,
                 const __hip_bfloat16* __restrict__ K,
                 const __hip_bfloat16* __restrict__ VT,
                 const unsigned char* __restrict__ kpm,
                 __hip_bfloat16* __restrict__ O)
{
    __shared__ __hip_bfloat16 Ks[2][64 * 64];
    __shared__ __hip_bfloat16 VTs[2][64 * 64];
    __shared__ __hip_bfloat16 Plds[8][32 * 64];

    const int tid = threadIdx.x;
    const int lane = tid & 63;
    const int w = tid >> 6;
    const int g = lane >> 4, lr = lane & 15;

    const int orig = blockIdx.y * 8 + blockIdx.x;
    const int nl = (orig & 7) * 64 + (orig >> 3);
    const int qb = nl & 7;
    const int bh = nl >> 3;

    const int b = bh >> 4, h = bh & 15;
    const int q0 = qb * 256 + w * 32;
    const size_t tokbase = (size_t)b * 2048;
    const __hip_bfloat16* VTbh = VT + (size_t)bh * 64 * 2048;

    unsigned tmask = 0;
#pragma unroll
    for (int i = 0; i < 8; ++i) {
        const unsigned mv = *(const unsigned*)(kpm + tokbase + i * 256 + lane * 4);
        const unsigned long long bal = __ballot((int)(mv != 0u));
#pragma unroll
        for (int j = 0; j < 4; ++j)
            if ((bal >> (16 * j)) & 0xFFFFull) tmask |= (1u << (i * 4 + j));
    }

    bf16x8 qf[2][2];
#pragma unroll
    for (int qn = 0; qn < 2; ++qn)
#pragma unroll
        for (int f = 0; f < 2; ++f)
            qf[qn][f] = *(const bf16x8*)(Q + (tokbase + q0 + qn * 16 + lr) * 1024 +
                                         h * 64 + f * 32 + g * 8);

    f32x4 o[2][4];
    const f32x4 zero = {0.f, 0.f, 0.f, 0.f};
#pragma unroll
    for (int qa = 0; qa < 2; ++qa)
#pragma unroll
        for (int nd = 0; nd < 4; ++nd) o[qa][nd] = zero;
    float m_run[2], l_part[2];
#pragma unroll
    for (int qn = 0; qn < 2; ++qn) { m_run[qn] = -1e30f; l_part[qn] = 0.f; }

    __hip_bfloat16* Pw = Plds[w];

    const int srow = w * 8 + (lane >> 3);
    const int sblk = (lane & 7) ^ (srow & 7);
    const __hip_bfloat16* Ksrc = K + (tokbase + srow) * 1024 + h * 64 + sblk * 8;
    const __hip_bfloat16* Vsrc = VTbh + (size_t)srow * 2048 + sblk * 8;

    auto stage = [&](int bufi, int kv0) {
        gload_lds16(Ksrc + (size_t)kv0 * 1024, (char*)&Ks[bufi][w * 512] + lane * 16);
        gload_lds16(Vsrc + kv0, (char*)&VTs[bufi][w * 512] + lane * 16);
    };

    stage(0, 0);
    __syncthreads();
    int buf = 0;

    for (int t = 0; t < 32; ++t) {
        const int kv0 = t * 64;
        if (t < 31) stage(buf ^ 1, kv0 + 64);

        f32x4 st[4][2];
        __builtin_amdgcn_s_setprio(1);
#pragma unroll
        for (int km = 0; km < 4; ++km) {
            bf16x8 kf[2];
#pragma unroll
            for (int f = 0; f < 2; ++f)
                kf[f] = *(const bf16x8*)(&Ks[buf][(km * 16 + lr) * 64 +
                                                  (((f * 4 + g) ^ (lr & 7)) * 8)]);
#pragma unroll
            for (int qn = 0; qn < 2; ++qn) {
                st[km][qn] = MFMA(kf[0], qf[qn][0], zero, 0, 0, 0);
                st[km][qn] = MFMA(kf[1], qf[qn][1], st[km][qn], 0, 0, 0);
            }
        }
        __builtin_amdgcn_s_setprio(0);

        if (tmask & (1u << t)) {
            const float NEG = -1e30f;
#pragma unroll
            for (int km = 0; km < 4; ++km) {
                const unsigned mu = *(const unsigned*)(kpm + tokbase + kv0 + km * 16 + g * 4);
#pragma unroll
                for (int r = 0; r < 4; ++r) {
                    if ((mu >> (8 * r)) & 0xFFu) {
#pragma unroll
                        for (int qn = 0; qn < 2; ++qn) st[km][qn][r] = NEG;
                    }
                }
            }
        }

        float pm[2];
#pragma unroll
        for (int qn = 0; qn < 2; ++qn) {
            const float v1 = max3f(st[0][qn][0], st[0][qn][1], st[0][qn][2]);
            const float v2 = max3f(st[0][qn][3], st[1][qn][0], st[1][qn][1]);
            const float v3 = max3f(st[1][qn][2], st[1][qn][3], st[2][qn][0]);
            const float v4 = max3f(st[2][qn][1], st[2][qn][2], st[2][qn][3]);
            const float v5 = max3f(st[3][qn][0], st[3][qn][1], st[3][qn][2]);
            pm[qn] = fmaxf(max3f(v1, v2, v3), max3f(v4, v5, st[3][qn][3]));
        }
        const int trig = (pm[0] > m_run[0] + 8.f) | (pm[1] > m_run[1] + 8.f);
        if (__any(trig)) {
            float alpha_q[2];
#pragma unroll
            for (int qn = 0; qn < 2; ++qn) {
                float rm = pm[qn];
                rm = fmaxf(rm, __shfl_xor(rm, 16));
                rm = fmaxf(rm, __shfl_xor(rm, 32));
                const float mnew = fmaxf(m_run[qn], rm);
                const float al = fexp2(m_run[qn] - mnew);
                l_part[qn] *= al;
                m_run[qn] = mnew;
                alpha_q[qn] = al;
            }
#pragma unroll
            for (int qa = 0; qa < 2; ++qa)
#pragma unroll
                for (int r = 0; r < 4; ++r) {
                    const float av = __shfl(alpha_q[qa], g * 4 + r, 16);
#pragma unroll
                    for (int nd = 0; nd < 4; ++nd) o[qa][nd][r] *= av;
                }
        }

#pragma unroll
        for (int qn = 0; qn < 2; ++qn) {
            const float mm = m_run[qn];
            const f32x2 mm2 = {mm, mm};
            f32x2 lacc = {0.f, 0.f};
#pragma unroll
            for (int km = 0; km < 4; ++km) {
                const f32x2 s01 = {st[km][qn][0], st[km][qn][1]};
                const f32x2 s23 = {st[km][qn][2], st[km][qn][3]};
                const f32x2 d01 = pk_sub2(s01, mm2);
                const f32x2 d23 = pk_sub2(s23, mm2);
                f32x2 p01, p23;
                p01.x = fexp2(d01.x);
                p01.y = fexp2(d01.y);
                p23.x = fexp2(d23.x);
                p23.y = fexp2(d23.y);
                lacc = pk_add2(lacc, pk_add2(p01, p23));
                uint2 pk;
                pk.x = cvtpk_bf16(p01.x, p01.y);
                pk.y = cvtpk_bf16(p23.x, p23.y);
                const int cs = (km * 2 + (g >> 1)) ^ (lr & 7);
                *(uint2*)(Pw + (qn * 16 + lr) * 64 + cs * 8 + (g & 1) * 4) = pk;
            }
            l_part[qn] += lacc.x + lacc.y;
        }

        __builtin_amdgcn_s_setprio(1);
#pragma unroll
        for (int f = 0; f < 2; ++f) {
            bf16x8 pa[2];
#pragma unroll
            for (int qa = 0; qa < 2; ++qa)
                pa[qa] = *(const bf16x8*)(Pw + (qa * 16 + lr) * 64 +
                                          (((f * 4 + g) ^ (lr & 7)) * 8));
#pragma unroll
            for (int nd = 0; nd < 4; ++nd) {
                bf16x8 vb = *(const bf16x8*)(&VTs[buf][(nd * 16 + lr) * 64 +
                                                       (((f * 4 + g) ^ (lr & 7)) * 8)]);
#pragma unroll
                for (int qa = 0; qa < 2; ++qa)
                    o[qa][nd] = MFMA(pa[qa], vb, o[qa][nd], 0, 0, 0);
            }
        }
        __builtin_amdgcn_s_setprio(0);

        __syncthreads();
        buf ^= 1;
    }

    float linv[2];
#pragma unroll
    for (int qn = 0; qn < 2; ++qn) {
        float lt = l_part[qn];
        lt += __shfl_xor(lt, 16);
        lt += __shfl_xor(lt, 32);
        linv[qn] = 1.0f / lt;
    }
#pragma unroll
    for (int qa = 0; qa < 2; ++qa)
#pragma unroll
        for (int r = 0; r < 4; ++r) {
            const float lv = __shfl(linv[qa], g * 4 + r, 16);
            const size_t row = tokbase + q0 + qa * 16 + g * 4 + r;
#pragma unroll
            for (int nd = 0; nd < 4; ++nd)
                O[row * 1024 + h * 64 + nd * 16 + lr] = __float2bfloat16(o[qa][nd][r] * lv);
        }
}

// ---------------- LayerNorm over bf16 input (f32 math) ----------------
__global__ __launch_bounds__(256)
void ln_b_kernel(const __hip_bfloat16* __restrict__ in, const float* __restrict__ gamma,
                 const float* __restrict__ beta, float* __restrict__ outf,
                 __hip_bfloat16* __restrict__ outb)
{
    const int row = blockIdx.x;
    const int tid = threadIdx.x;
    const ushort4 u = ((const ushort4*)(in + (size_t)row * 1024))[tid];
    float v0 = __bfloat162float(__builtin_bit_cast(__hip_bfloat16, u.x));
    float v1 = __bfloat162float(__builtin_bit_cast(__hip_bfloat16, u.y));
    float v2 = __bfloat162float(__builtin_bit_cast(__hip_bfloat16, u.z));
    float v3 = __bfloat162float(__builtin_bit_cast(__hip_bfloat16, u.w));
    float s = (v0 + v1) + (v2 + v3);
    float s2 = (v0 * v0 + v1 * v1) + (v2 * v2 + v3 * v3);
#pragma unroll
    for (int off = 1; off < 64; off <<= 1) {
        s += __shfl_xor(s, off);
        s2 += __shfl_xor(s2, off);
    }
    __shared__ float red[8];
    const int wv = tid >> 6;
    if ((tid & 63) == 0) { red[wv] = s; red[4 + wv] = s2; }
    __syncthreads();
    s = red[0] + red[1] + red[2] + red[3];
    s2 = red[4] + red[5] + red[6] + red[7];
    const float mean = s * (1.f / 1024.f);
    const float var = s2 * (1.f / 1024.f) - mean * mean;
    const float rstd = rsqrtf(var + 1e-5f);
    const float4 gm = ((const float4*)gamma)[tid];
    const float4 bt = ((const float4*)beta)[tid];
    float y0 = (v0 - mean) * rstd * gm.x + bt.x;
    float y1 = (v1 - mean) * rstd * gm.y + bt.y;
    float y2 = (v2 - mean) * rstd * gm.z + bt.z;
    float y3 = (v3 - mean) * rstd * gm.w + bt.w;
    if (outf) {
        float4 y; y.x = y0; y.y = y1; y.z = y2; y.w = y3;
        ((float4*)(outf + (size_t)row * 1024))[tid] = y;
    }
    if (outb) {
        ushort4 ub;
        ub.x = f2bfu(y0); ub.y = f2bfu(y1); ub.z = f2bfu(y2); ub.w = f2bfu(y3);
        ((ushort4*)outb)[row * 256 + tid] = ub;
    }
}

// ---------------- host ----------------
extern "C" void kernel_launch(void* const* d_in, const int* in_sizes, int n_in,
                              void* d_out, int out_size, void* d_ws, size_t ws_size,
                              hipStream_t stream)
{
    const float* x    = (const float*)d_in[0];
    const unsigned char* kpm = (const unsigned char*)d_in[1];
    const float* Wq = (const float*)d_in[2];
    const float* bq = (const float*)d_in[3];
    const float* Wk = (const float*)d_in[4];
    const float* bk = (const float*)d_in[5];
    const float* Wv = (const float*)d_in[6];
    const float* bv = (const float*)d_in[7];
    const float* Wo = (const float*)d_in[8];
    const float* bo = (const float*)d_in[9];
    const float* W1 = (const float*)d_in[10];
    const float* b1 = (const float*)d_in[11];
    const float* W2 = (const float*)d_in[12];
    const float* b2 = (const float*)d_in[13];
    const float* ln1g = (const float*)d_in[14];
    const float* ln1b = (const float*)d_in[15];
    const float* ln2g = (const float*)d_in[16];
    const float* ln2b = (const float*)d_in[17];
    float* out = (float*)d_out;

    char* ws = (char*)d_ws;
    const size_t SZ_ND2 = (size_t)8192 * 1024 * 2;
    size_t off = 0;
    __hip_bfloat16* xb  = (__hip_bfloat16*)(ws + off); off += SZ_ND2;
    __hip_bfloat16* wqb = (__hip_bfloat16*)(ws + off); off += (size_t)1024 * 1024 * 2;
    __hip_bfloat16* wkb = (__hip_bfloat16*)(ws + off); off += (size_t)1024 * 1024 * 2;
    __hip_bfloat16* wvb = (__hip_bfloat16*)(ws + off); off += (size_t)1024 * 1024 * 2;
    __hip_bfloat16* wob = (__hip_bfloat16*)(ws + off); off += (size_t)1024 * 1024 * 2;
    __hip_bfloat16* w1b = (__hip_bfloat16*)(ws + off); off += (size_t)4096 * 1024 * 2;
    __hip_bfloat16* w2b = (__hip_bfloat16*)(ws + off); off += (size_t)4096 * 1024 * 2;
    const size_t qkv0 = off;
    __hip_bfloat16* qbp = (__hip_bfloat16*)(ws + off); off += SZ_ND2;
    __hip_bfloat16* kbp = (__hip_bfloat16*)(ws + off); off += SZ_ND2;
    __hip_bfloat16* vtg = (__hip_bfloat16*)(ws + off); off += SZ_ND2;
    __hip_bfloat16* abp = (__hip_bfloat16*)(ws + off); off += SZ_ND2;
    __hip_bfloat16* hbp = (__hip_bfloat16*)(ws + qkv0);
    __hip_bfloat16* y1b = (__hip_bfloat16*)(ws + off); off += SZ_ND2;
    __hip_bfloat16* x1b = (__hip_bfloat16*)(ws + off); off += SZ_ND2;
    __hip_bfloat16* y2b = y1b;
    float* bqkv = (float*)(ws + off); off += 3072 * 4;

    cvt_all_kernel<<<20480, 256, 0, stream>>>(
        (const float4*)x,  (ushort4*)xb,
        (const float4*)Wq, (ushort4*)wqb,
        (const float4*)Wk, (ushort4*)wkb,
        (const float4*)Wv, (ushort4*)wvb,
        (const float4*)Wo, (ushort4*)wob,
        (const float4*)W1, (ushort4*)w1b,
        (const float4*)W2, (ushort4*)w2b);
    hipMemcpyAsync(bqkv,        bq, 4096, hipMemcpyDeviceToDevice, stream);
    hipMemcpyAsync(bqkv + 1024, bk, 4096, hipMemcpyDeviceToDevice, stream);
    hipMemcpyAsync(bqkv + 2048, bv, 4096, hipMemcpyDeviceToDevice, stream);

    dim3 blk(256);
    const float qscale = 0.125f * 1.44269504088896f;

    // QKV back on gemm_bt (384-block gemm8p grid was a half-idle tail: R22 regression)
    gemm_bt<EPI_QKV><<<dim3(64, 24), blk, 0, stream>>>(
        xb, wqb, bqkv, nullptr, qscale, qbp, kbp, vtg, 8192, 3072, 1024);

    attn_flash3<<<dim3(8, 64), 512, 0, stream>>>(qbp, kbp, vtg, kpm, abp);

    gemm_bt<EPI_RES_OB><<<dim3(64, 8), blk, 0, stream>>>(
        abp, wob, bo, xb, 1.0f, y1b, nullptr, nullptr, 8192, 1024, 1024);
    ln_b_kernel<<<8192, 256, 0, stream>>>(y1b, ln1g, ln1b, nullptr, x1b);

    // FFN1 on the proven 8-phase 256^2 kernel (512 blocks = 2 full rounds)
    gemm8p<EPI_GELU><<<dim3(32, 16), 512, 0, stream>>>(
        x1b, w1b, b1, nullptr, 1.0f, hbp, 8192, 4096, 1024);
    // FFN2 on the 128x256 2-phase kernel (64x4 = 256 blocks = exactly 1/CU)
    gemm2p_w<EPI_RES_OB><<<dim3(64, 4), 512, 0, stream>>>(
        hbp, w2b, b2, x1b, y2b, 8192, 1024, 4096);
    ln_b_kernel<<<8192, 256, 0, stream>>>(y2b, ln2g, ln2b, out, nullptr);
}

// Round 25
// 369.191 us; speedup vs baseline: 1.0123x; 1.0123x over previous
//
#include <hip/hip_runtime.h>
#include <hip/hip_bf16.h>
#include <math.h>

typedef short bf16x8 __attribute__((ext_vector_type(8)));
typedef float f32x4 __attribute__((ext_vector_type(4)));
typedef float f32x2 __attribute__((ext_vector_type(2)));

__device__ __forceinline__ unsigned short f2bfu(float f) {
    __hip_bfloat16 h = __float2bfloat16(f);
    return __builtin_bit_cast(unsigned short, h);
}

__device__ __forceinline__ float fexp2(float x) {
    float r;
    asm("v_exp_f32 %0, %1" : "=v"(r) : "v"(x));
    return r;
}

__device__ __forceinline__ unsigned cvtpk_bf16(float lo, float hi) {
    unsigned r;
    asm("v_cvt_pk_bf16_f32 %0, %1, %2" : "=v"(r) : "v"(lo), "v"(hi));
    return r;
}

__device__ __forceinline__ float max3f(float a, float b, float c) {
    float r;
    asm("v_max3_f32 %0, %1, %2, %3" : "=v"(r) : "v"(a), "v"(b), "v"(c));
    return r;
}

__device__ __forceinline__ f32x2 pk_sub2(f32x2 a, f32x2 b) {
    f32x2 r;
    asm("v_pk_add_f32 %0, %1, %2 neg_lo:[0,1] neg_hi:[0,1]" : "=v"(r) : "v"(a), "v"(b));
    return r;
}

__device__ __forceinline__ f32x2 pk_add2(f32x2 a, f32x2 b) {
    f32x2 r;
    asm("v_pk_add_f32 %0, %1, %2" : "=v"(r) : "v"(a), "v"(b));
    return r;
}

__device__ __forceinline__ float gelu_fast(float x) {
    const float x2 = x * x;
    const float z = x * (0.7978845608f + 0.0356774081f * x2);
    const float e = fexp2(z * 2.88539008f);
    const float r = __builtin_amdgcn_rcpf(e + 1.0f);
    return x * (1.0f - r);
}

__device__ __forceinline__ void gload_lds16(const void* gsrc, void* ldst) {
    __builtin_amdgcn_global_load_lds((const __attribute__((address_space(1))) void*)gsrc,
                                     (__attribute__((address_space(3))) void*)ldst,
                                     16, 0, 0);
}

#define MFMA __builtin_amdgcn_mfma_f32_16x16x32_bf16
#define SBAR __builtin_amdgcn_s_barrier
#define SCHB __builtin_amdgcn_sched_barrier

// ---------------- fused f32 -> bf16 convert (all 7 tensors, one launch) ----------------
__global__ __launch_bounds__(256)
void cvt_all_kernel(const float4* __restrict__ x,  ushort4* __restrict__ xb,
                    const float4* __restrict__ wq, ushort4* __restrict__ wqb,
                    const float4* __restrict__ wk, ushort4* __restrict__ wkb,
                    const float4* __restrict__ wv, ushort4* __restrict__ wvb,
                    const float4* __restrict__ wo, ushort4* __restrict__ wob,
                    const float4* __restrict__ w1, ushort4* __restrict__ w1b,
                    const float4* __restrict__ w2, ushort4* __restrict__ w2b)
{
    const int i = blockIdx.x * 256 + threadIdx.x;
    const float4* src;
    ushort4* dst;
    int base;
    if (i < 2097152)      { src = x;  dst = xb;  base = 0; }
    else if (i < 2359296) { src = wq; dst = wqb; base = 2097152; }
    else if (i < 2621440) { src = wk; dst = wkb; base = 2359296; }
    else if (i < 2883584) { src = wv; dst = wvb; base = 2621440; }
    else if (i < 3145728) { src = wo; dst = wob; base = 2883584; }
    else if (i < 4194304) { src = w1; dst = w1b; base = 3145728; }
    else                  { src = w2; dst = w2b; base = 4194304; }
    const float4 v = src[i - base];
    ushort4 o;
    o.x = f2bfu(v.x); o.y = f2bfu(v.y); o.z = f2bfu(v.z); o.w = f2bfu(v.w);
    dst[i - base] = o;
}

enum { EPI_QKV = 0, EPI_RES_OB = 2, EPI_GELU = 3 };

// ======== 256x256 8-phase GEMM, 4Mx2N waves (proven R18 kernel, FFN1) ========
template<int EPI>
__global__ __launch_bounds__(512, 1)
void gemm8p(const __hip_bfloat16* __restrict__ A,
            const __hip_bfloat16* __restrict__ W,
            const float* __restrict__ bias,
            const void* __restrict__ resv,
            float scale,
            void* __restrict__ outp,
            int M, int N, int K)
{
    __shared__ __hip_bfloat16 As[2][256 * 64];
    __shared__ __hip_bfloat16 Bs[2][256 * 64];
    const int tid = threadIdx.x;
    const int lane = tid & 63;
    const int wid = tid >> 6;
    const int wr = wid >> 1;
    const int wc = wid & 1;
    const int g = lane >> 4, lr = lane & 15;
    const int row0 = blockIdx.x * 256;
    const int col0 = blockIdx.y * 256;

    f32x4 acc[4][8];
    const f32x4 zero = {0.f, 0.f, 0.f, 0.f};
#pragma unroll
    for (int m = 0; m < 4; ++m)
#pragma unroll
        for (int n = 0; n < 8; ++n) acc[m][n] = zero;

    const int arl = tid >> 3;
    const int agc = (tid & 7) ^ (arl & 7);
    const __hip_bfloat16* Abase = A + (size_t)(row0 + arl) * K + agc * 8;
    const __hip_bfloat16* Bbase = W + (size_t)(col0 + arl) * K + agc * 8;

    auto stageA = [&](int bi, int kt) {
#pragma unroll
        for (int q = 0; q < 4; ++q)
            gload_lds16(Abase + (size_t)(q * 64) * K + kt * 64,
                        (char*)As[bi] + q * 8192 + tid * 16);
    };
    auto stageB = [&](int bi, int h, int kt) {
#pragma unroll
        for (int j = 0; j < 2; ++j)
            gload_lds16(Bbase + (size_t)(h * 128 + j * 64) * K + kt * 64,
                        (char*)Bs[bi] + h * 16384 + j * 8192 + tid * 16);
    };

    const int NT = K >> 6;
    stageA(0, 0);
    stageB(0, 0, 0);
    stageB(0, 1, 0);
    stageA(1, 1);
    asm volatile("s_waitcnt vmcnt(4)" ::: "memory");
    SBAR();
    SCHB(0);

    const int swz = lr & 7;
    const int arow = wr * 64;
    const int brow = wc * 128;

    for (int t = 0; t < NT; ++t) {
        const int bi = t & 1;
        const __hip_bfloat16* Ab = As[bi];
        const __hip_bfloat16* Bb = Bs[bi];
        bf16x8 a[4], b0[4], b1[4];

#pragma unroll
        for (int m = 0; m < 4; ++m)
            a[m] = *(const bf16x8*)(Ab + (arow + m * 16 + lr) * 64 + ((g ^ swz) * 8));
#pragma unroll
        for (int n = 0; n < 4; ++n)
            b0[n] = *(const bf16x8*)(Bb + (brow + n * 16 + lr) * 64 + ((g ^ swz) * 8));
        if (t + 1 < NT) stageB(bi ^ 1, 0, t + 1);
        SCHB(0);
        SBAR();
        __builtin_amdgcn_s_setprio(1);
#pragma unroll
        for (int m = 0; m < 4; ++m)
#pragma unroll
            for (int n = 0; n < 4; ++n)
                acc[m][n] = MFMA(a[m], b0[n], acc[m][n], 0, 0, 0);
        __builtin_amdgcn_s_setprio(0);
        SBAR();

#pragma unroll
        for (int n = 0; n < 4; ++n)
            b1[n] = *(const bf16x8*)(Bb + (brow + (n + 4) * 16 + lr) * 64 + ((g ^ swz) * 8));
        if (t + 1 < NT) stageB(bi ^ 1, 1, t + 1);
        SCHB(0);
        SBAR();
        __builtin_amdgcn_s_setprio(1);
#pragma unroll
        for (int m = 0; m < 4; ++m)
#pragma unroll
            for (int n = 0; n < 4; ++n)
                acc[m][n + 4] = MFMA(a[m], b1[n], acc[m][n + 4], 0, 0, 0);
        __builtin_amdgcn_s_setprio(0);
        SBAR();

#pragma unroll
        for (int m = 0; m < 4; ++m)
            a[m] = *(const bf16x8*)(Ab + (arow + m * 16 + lr) * 64 + (((4 + g) ^ swz) * 8));
#pragma unroll
        for (int n = 0; n < 4; ++n)
            b0[n] = *(const bf16x8*)(Bb + (brow + n * 16 + lr) * 64 + (((4 + g) ^ swz) * 8));
        SCHB(0);
        SBAR();
        __builtin_amdgcn_s_setprio(1);
#pragma unroll
        for (int m = 0; m < 4; ++m)
#pragma unroll
            for (int n = 0; n < 4; ++n)
                acc[m][n] = MFMA(a[m], b0[n], acc[m][n], 0, 0, 0);
        __builtin_amdgcn_s_setprio(0);
        SBAR();

#pragma unroll
        for (int n = 0; n < 4; ++n)
            b1[n] = *(const bf16x8*)(Bb + (brow + (n + 4) * 16 + lr) * 64 + (((4 + g) ^ swz) * 8));
        if (t + 2 < NT) stageA(bi, t + 2);
        SCHB(0);
        SBAR();
        __builtin_amdgcn_s_setprio(1);
#pragma unroll
        for (int m = 0; m < 4; ++m)
#pragma unroll
            for (int n = 0; n < 4; ++n)
                acc[m][n + 4] = MFMA(a[m], b1[n], acc[m][n + 4], 0, 0, 0);
        __builtin_amdgcn_s_setprio(0);
        if (t + 1 < NT) {
            if (t + 2 < NT) asm volatile("s_waitcnt vmcnt(4)" ::: "memory");
            else            asm volatile("s_waitcnt vmcnt(0)" ::: "memory");
            SBAR();
            SCHB(0);
        }
    }

#pragma unroll
    for (int n = 0; n < 8; ++n) {
        const int cc = col0 + wc * 128 + n * 16 + lr;
        const float bv = bias[cc];
#pragma unroll
        for (int m = 0; m < 4; ++m) {
            const int rbase = row0 + wr * 64 + m * 16 + g * 4;
#pragma unroll
            for (int r = 0; r < 4; ++r) {
                const size_t idx = (size_t)(rbase + r) * N + cc;
                float v = acc[m][n][r] + bv;
                if (EPI == EPI_RES_OB) {
                    const float rv = __bfloat162float(((const __hip_bfloat16*)resv)[idx]);
                    ((__hip_bfloat16*)outp)[idx] = __float2bfloat16(v + rv);
                } else if (EPI == EPI_GELU) {
                    ((__hip_bfloat16*)outp)[idx] = __float2bfloat16(gelu_fast(v));
                }
            }
        }
    }
}

// ======== 128x256 2-phase 8-wave GEMM (QKV/proj/FFN2: exact-fit grids) ========
// 8 waves as 2Mx4N; wave owns 64x64 -> acc[4][4]. BK=64, NT=K/64.
// A: 3-buffer rotation As[t%3]; B: 2-buffer Bs[t&1]; 112KB LDS, 1 blk/CU.
// P1 {read ks0; stage B(t+1); bar; 16 MFMA; bar}
// P2 {read ks1; stage A(t+2); bar; 16 MFMA; vmcnt(2); bar}
template<int EPI>
__global__ __launch_bounds__(512, 1)
void gemm2p_w(const __hip_bfloat16* __restrict__ A,
              const __hip_bfloat16* __restrict__ W,
              const float* __restrict__ bias,
              const void* __restrict__ resv,
              float scale,
              void* __restrict__ outp, void* __restrict__ outp2, void* __restrict__ outp3,
              int M, int N, int K)
{
    __shared__ __hip_bfloat16 As[3][128 * 64];
    __shared__ __hip_bfloat16 Bs[2][256 * 64];
    const int tid = threadIdx.x;
    const int lane = tid & 63;
    const int wid = tid >> 6;
    const int wr = wid >> 2;          // 0..1 : 64-row band
    const int wc = wid & 3;           // 0..3 : 64-col band
    const int g = lane >> 4, lr = lane & 15;
    const int row0 = blockIdx.x * 128;
    const int col0 = blockIdx.y * 256;

    f32x4 acc[4][4];
    const f32x4 zero = {0.f, 0.f, 0.f, 0.f};
#pragma unroll
    for (int m = 0; m < 4; ++m)
#pragma unroll
        for (int n = 0; n < 4; ++n) acc[m][n] = zero;

    const int r0 = tid >> 3;
    const int gc = (tid & 7) ^ (r0 & 7);
    const __hip_bfloat16* Abase = A + (size_t)(row0 + r0) * K + gc * 8;
    const __hip_bfloat16* Bbase = W + (size_t)(col0 + r0) * K + gc * 8;

    auto stageA = [&](int bi, int kt) {
#pragma unroll
        for (int j = 0; j < 2; ++j)
            gload_lds16(Abase + (size_t)(j * 64) * K + kt * 64,
                        (char*)As[bi] + j * 8192 + tid * 16);
    };
    auto stageB = [&](int bi, int kt) {
#pragma unroll
        for (int j = 0; j < 4; ++j)
            gload_lds16(Bbase + (size_t)(j * 64) * K + kt * 64,
                        (char*)Bs[bi] + j * 8192 + tid * 16);
    };

    const int NT = K >> 6;
    stageA(0, 0);
    stageB(0, 0);
    stageA(1, 1);
    asm volatile("s_waitcnt vmcnt(2)" ::: "memory");
    SBAR();
    SCHB(0);

    const int swz = lr & 7;
    const int arow = wr * 64;
    const int brow = wc * 64;
    int a_cur = 0;

    for (int t = 0; t < NT; ++t) {
        const int bu = t & 1;
        const __hip_bfloat16* Ab = As[a_cur];
        const __hip_bfloat16* Bb = Bs[bu];
        const int a_nx2 = (a_cur == 0) ? 2 : a_cur - 1;   // (t+2)%3
        bf16x8 a[4], b[4];

        // ---- P1 (ks0)
#pragma unroll
        for (int m = 0; m < 4; ++m)
            a[m] = *(const bf16x8*)(Ab + (arow + m * 16 + lr) * 64 + ((g ^ swz) * 8));
#pragma unroll
        for (int n = 0; n < 4; ++n)
            b[n] = *(const bf16x8*)(Bb + (brow + n * 16 + lr) * 64 + ((g ^ swz) * 8));
        if (t + 1 < NT) stageB(bu ^ 1, t + 1);
        SCHB(0);
        SBAR();
        __builtin_amdgcn_s_setprio(1);
#pragma unroll
        for (int m = 0; m < 4; ++m)
#pragma unroll
            for (int n = 0; n < 4; ++n)
                acc[m][n] = MFMA(a[m], b[n], acc[m][n], 0, 0, 0);
        __builtin_amdgcn_s_setprio(0);
        SBAR();

        // ---- P2 (ks1)
#pragma unroll
        for (int m = 0; m < 4; ++m)
            a[m] = *(const bf16x8*)(Ab + (arow + m * 16 + lr) * 64 + (((4 + g) ^ swz) * 8));
#pragma unroll
        for (int n = 0; n < 4; ++n)
            b[n] = *(const bf16x8*)(Bb + (brow + n * 16 + lr) * 64 + (((4 + g) ^ swz) * 8));
        if (t + 2 < NT) stageA(a_nx2, t + 2);
        SCHB(0);
        SBAR();
        __builtin_amdgcn_s_setprio(1);
#pragma unroll
        for (int m = 0; m < 4; ++m)
#pragma unroll
            for (int n = 0; n < 4; ++n)
                acc[m][n] = MFMA(a[m], b[n], acc[m][n], 0, 0, 0);
        __builtin_amdgcn_s_setprio(0);
        if (t + 1 < NT) {
            if (t + 2 < NT) asm volatile("s_waitcnt vmcnt(2)" ::: "memory");
            else            asm volatile("s_waitcnt vmcnt(0)" ::: "memory");
            SBAR();
            SCHB(0);
        }
        a_cur = (a_cur == 2) ? 0 : a_cur + 1;
    }

    // ---- epilogue
#pragma unroll
    for (int n = 0; n < 4; ++n) {
        const int cc = col0 + wc * 64 + n * 16 + lr;
        const float bv = bias[cc];
#pragma unroll
        for (int m = 0; m < 4; ++m) {
            const int rbase = row0 + wr * 64 + m * 16 + g * 4;
            if (EPI == EPI_QKV) {
                const int seg = col0 >> 10;   // block-uniform (256-col tile in one segment)
                if (seg == 2) {
                    ushort4 u;
                    u.x = f2bfu(acc[m][n][0] + bv);
                    u.y = f2bfu(acc[m][n][1] + bv);
                    u.z = f2bfu(acc[m][n][2] + bv);
                    u.w = f2bfu(acc[m][n][3] + bv);
                    const int cc2 = cc - 2048;
                    const int h_ = cc2 >> 6, dh = cc2 & 63;
                    const int bb = rbase >> 11;
                    const int s = rbase & 2047;
                    *(ushort4*)((__hip_bfloat16*)outp3 +
                                (((size_t)bb * 16 + h_) * 64 + dh) * 2048 + s) = u;
                } else {
                    const float sc = (seg == 0) ? scale : 1.0f;
                    __hip_bfloat16* dst = (seg == 0) ? (__hip_bfloat16*)outp
                                                     : (__hip_bfloat16*)outp2;
                    const int ccl = cc & 1023;
#pragma unroll
                    for (int r = 0; r < 4; ++r)
                        dst[(size_t)(rbase + r) * 1024 + ccl] =
                            __float2bfloat16((acc[m][n][r] + bv) * sc);
                }
            } else {
#pragma unroll
                for (int r = 0; r < 4; ++r) {
                    const size_t idx = (size_t)(rbase + r) * N + cc;
                    float v = acc[m][n][r] + bv;
                    if (EPI == EPI_RES_OB) {
                        const float rv = __bfloat162float(((const __hip_bfloat16*)resv)[idx]);
                        ((__hip_bfloat16*)outp)[idx] = __float2bfloat16(v + rv);
                    } else if (EPI == EPI_GELU) {
                        ((__hip_bfloat16*)outp)[idx] = __float2bfloat16(gelu_fast(v));
                    }
                }
            }
        }
    }
}

// ---------------- Flash attention v3: 8 waves x 32 q-rows ----------------
__global__ __launch_bounds__(512, 4)
void attn_flash3(const __hip_bfloat16* __restrict__ Q,
                 const __hip_bfloat16* __restrict__ K,
                 const __hip_bfloat16* __restrict__ VT,
                 const unsigned char* __restrict__ kpm,
                 __hip_bfloat16* __restrict__ O)
{
    __shared__ __hip_bfloat16 Ks[2][64 * 64];
    __shared__ __hip_bfloat16 VTs[2][64 * 64];
    __shared__ __hip_bfloat16 Plds[8][32 * 64];

    const int tid = threadIdx.x;
    const int lane = tid & 63;
    const int w = tid >> 6;
    const int g = lane >> 4, lr = lane & 15;

    const int orig = blockIdx.y * 8 + blockIdx.x;
    const int nl = (orig & 7) * 64 + (orig >> 3);
    const int qb = nl & 7;
    const int bh = nl >> 3;

    const int b = bh >> 4, h = bh & 15;
    const int q0 = qb * 256 + w * 32;
    const size_t tokbase = (size_t)b * 2048;
    const __hip_bfloat16* VTbh = VT + (size_t)bh * 64 * 2048;

    unsigned tmask = 0;
#pragma unroll
    for (int i = 0; i < 8; ++i) {
        const unsigned mv = *(const unsigned*)(kpm + tokbase + i * 256 + lane * 4);
        const unsigned long long bal = __ballot((int)(mv != 0u));
#pragma unroll
        for (int j = 0; j < 4; ++j)
            if ((bal >> (16 * j)) & 0xFFFFull) tmask |= (1u << (i * 4 + j));
    }

    bf16x8 qf[2][2];
#pragma unroll
    for (int qn = 0; qn < 2; ++qn)
#pragma unroll
        for (int f = 0; f < 2; ++f)
            qf[qn][f] = *(const bf16x8*)(Q + (tokbase + q0 + qn * 16 + lr) * 1024 +
                                         h * 64 + f * 32 + g * 8);

    f32x4 o[2][4];
    const f32x4 zero = {0.f, 0.f, 0.f, 0.f};
#pragma unroll
    for (int qa = 0; qa < 2; ++qa)
#pragma unroll
        for (int nd = 0; nd < 4; ++nd) o[qa][nd] = zero;
    float m_run[2], l_part[2];
#pragma unroll
    for (int qn = 0; qn < 2; ++qn) { m_run[qn] = -1e30f; l_part[qn] = 0.f; }

    __hip_bfloat16* Pw = Plds[w];

    const int srow = w * 8 + (lane >> 3);
    const int sblk = (lane & 7) ^ (srow & 7);
    const __hip_bfloat16* Ksrc = K + (tokbase + srow) * 1024 + h * 64 + sblk * 8;
    const __hip_bfloat16* Vsrc = VTbh + (size_t)srow * 2048 + sblk * 8;

    auto stage = [&](int bufi, int kv0) {
        gload_lds16(Ksrc + (size_t)kv0 * 1024, (char*)&Ks[bufi][w * 512] + lane * 16);
        gload_lds16(Vsrc + kv0, (char*)&VTs[bufi][w * 512] + lane * 16);
    };

    stage(0, 0);
    __syncthreads();
    int buf = 0;

    for (int t = 0; t < 32; ++t) {
        const int kv0 = t * 64;
        if (t < 31) stage(buf ^ 1, kv0 + 64);

        f32x4 st[4][2];
        __builtin_amdgcn_s_setprio(1);
#pragma unroll
        for (int km = 0; km < 4; ++km) {
            bf16x8 kf[2];
#pragma unroll
            for (int f = 0; f < 2; ++f)
                kf[f] = *(const bf16x8*)(&Ks[buf][(km * 16 + lr) * 64 +
                                                  (((f * 4 + g) ^ (lr & 7)) * 8)]);
#pragma unroll
            for (int qn = 0; qn < 2; ++qn) {
                st[km][qn] = MFMA(kf[0], qf[qn][0], zero, 0, 0, 0);
                st[km][qn] = MFMA(kf[1], qf[qn][1], st[km][qn], 0, 0, 0);
            }
        }
        __builtin_amdgcn_s_setprio(0);

        if (tmask & (1u << t)) {
            const float NEG = -1e30f;
#pragma unroll
            for (int km = 0; km < 4; ++km) {
                const unsigned mu = *(const unsigned*)(kpm + tokbase + kv0 + km * 16 + g * 4);
#pragma unroll
                for (int r = 0; r < 4; ++r) {
                    if ((mu >> (8 * r)) & 0xFFu) {
#pragma unroll
                        for (int qn = 0; qn < 2; ++qn) st[km][qn][r] = NEG;
                    }
                }
            }
        }

        float pm[2];
#pragma unroll
        for (int qn = 0; qn < 2; ++qn) {
            const float v1 = max3f(st[0][qn][0], st[0][qn][1], st[0][qn][2]);
            const float v2 = max3f(st[0][qn][3], st[1][qn][0], st[1][qn][1]);
            const float v3 = max3f(st[1][qn][2], st[1][qn][3], st[2][qn][0]);
            const float v4 = max3f(st[2][qn][1], st[2][qn][2], st[2][qn][3]);
            const float v5 = max3f(st[3][qn][0], st[3][qn][1], st[3][qn][2]);
            pm[qn] = fmaxf(max3f(v1, v2, v3), max3f(v4, v5, st[3][qn][3]));
        }
        const int trig = (pm[0] > m_run[0] + 8.f) | (pm[1] > m_run[1] + 8.f);
        if (__any(trig)) {
            float alpha_q[2];
#pragma unroll
            for (int qn = 0; qn < 2; ++qn) {
                float rm = pm[qn];
                rm = fmaxf(rm, __shfl_xor(rm, 16));
                rm = fmaxf(rm, __shfl_xor(rm, 32));
                const float mnew = fmaxf(m_run[qn], rm);
                const float al = fexp2(m_run[qn] - mnew);
                l_part[qn] *= al;
                m_run[qn] = mnew;
                alpha_q[qn] = al;
            }
#pragma unroll
            for (int qa = 0; qa < 2; ++qa)
#pragma unroll
                for (int r = 0; r < 4; ++r) {
                    const float av = __shfl(alpha_q[qa], g * 4 + r, 16);
#pragma unroll
                    for (int nd = 0; nd < 4; ++nd) o[qa][nd][r] *= av;
                }
        }

#pragma unroll
        for (int qn = 0; qn < 2; ++qn) {
            const float mm = m_run[qn];
            const f32x2 mm2 = {mm, mm};
            f32x2 lacc = {0.f, 0.f};
#pragma unroll
            for (int km = 0; km < 4; ++km) {
                const f32x2 s01 = {st[km][qn][0], st[km][qn][1]};
                const f32x2 s23 = {st[km][qn][2], st[km][qn][3]};
                const f32x2 d01 = pk_sub2(s01, mm2);
                const f32x2 d23 = pk_sub2(s23, mm2);
                f32x2 p01, p23;
                p01.x = fexp2(d01.x);
                p01.y = fexp2(d01.y);
                p23.x = fexp2(d23.x);
                p23.y = fexp2(d23.y);
                lacc = pk_add2(lacc, pk_add2(p01, p23));
                uint2 pk;
                pk.x = cvtpk_bf16(p01.x, p01.y);
                pk.y = cvtpk_bf16(p23.x, p23.y);
                const int cs = (km * 2 + (g >> 1)) ^ (lr & 7);
                *(uint2*)(Pw + (qn * 16 + lr) * 64 + cs * 8 + (g & 1) * 4) = pk;
            }
            l_part[qn] += lacc.x + lacc.y;
        }

        __builtin_amdgcn_s_setprio(1);
#pragma unroll
        for (int f = 0; f < 2; ++f) {
            bf16x8 pa[2];
#pragma unroll
            for (int qa = 0; qa < 2; ++qa)
                pa[qa] = *(const bf16x8*)(Pw + (qa * 16 + lr) * 64 +
                                          (((f * 4 + g) ^ (lr & 7)) * 8));
#pragma unroll
            for (int nd = 0; nd < 4; ++nd) {
                bf16x8 vb = *(const bf16x8*)(&VTs[buf][(nd * 16 + lr) * 64 +
                                                       (((f * 4 + g) ^ (lr & 7)) * 8)]);
#pragma unroll
                for (int qa = 0; qa < 2; ++qa)
                    o[qa][nd] = MFMA(pa[qa], vb, o[qa][nd], 0, 0, 0);
            }
        }
        __builtin_amdgcn_s_setprio(0);

        __syncthreads();
        buf ^= 1;
    }

    float linv[2];
#pragma unroll
    for (int qn = 0; qn < 2; ++qn) {
        float lt = l_part[qn];
        lt += __shfl_xor(lt, 16);
        lt += __shfl_xor(lt, 32);
        linv[qn] = 1.0f / lt;
    }
#pragma unroll
    for (int qa = 0; qa < 2; ++qa)
#pragma unroll
        for (int r = 0; r < 4; ++r) {
            const float lv = __shfl(linv[qa], g * 4 + r, 16);
            const size_t row = tokbase + q0 + qa * 16 + g * 4 + r;
#pragma unroll
            for (int nd = 0; nd < 4; ++nd)
                O[row * 1024 + h * 64 + nd * 16 + lr] = __float2bfloat16(o[qa][nd][r] * lv);
        }
}

// ---------------- LayerNorm over bf16 input (f32 math) ----------------
__global__ __launch_bounds__(256)
void ln_b_kernel(const __hip_bfloat16* __restrict__ in, const float* __restrict__ gamma,
                 const float* __restrict__ beta, float* __restrict__ outf,
                 __hip_bfloat16* __restrict__ outb)
{
    const int row = blockIdx.x;
    const int tid = threadIdx.x;
    const ushort4 u = ((const ushort4*)(in + (size_t)row * 1024))[tid];
    float v0 = __bfloat162float(__builtin_bit_cast(__hip_bfloat16, u.x));
    float v1 = __bfloat162float(__builtin_bit_cast(__hip_bfloat16, u.y));
    float v2 = __bfloat162float(__builtin_bit_cast(__hip_bfloat16, u.z));
    float v3 = __bfloat162float(__builtin_bit_cast(__hip_bfloat16, u.w));
    float s = (v0 + v1) + (v2 + v3);
    float s2 = (v0 * v0 + v1 * v1) + (v2 * v2 + v3 * v3);
#pragma unroll
    for (int off = 1; off < 64; off <<= 1) {
        s += __shfl_xor(s, off);
        s2 += __shfl_xor(s2, off);
    }
    __shared__ float red[8];
    const int wv = tid >> 6;
    if ((tid & 63) == 0) { red[wv] = s; red[4 + wv] = s2; }
    __syncthreads();
    s = red[0] + red[1] + red[2] + red[3];
    s2 = red[4] + red[5] + red[6] + red[7];
    const float mean = s * (1.f / 1024.f);
    const float var = s2 * (1.f / 1024.f) - mean * mean;
    const float rstd = rsqrtf(var + 1e-5f);
    const float4 gm = ((const float4*)gamma)[tid];
    const float4 bt = ((const float4*)beta)[tid];
    float y0 = (v0 - mean) * rstd * gm.x + bt.x;
    float y1 = (v1 - mean) * rstd * gm.y + bt.y;
    float y2 = (v2 - mean) * rstd * gm.z + bt.z;
    float y3 = (v3 - mean) * rstd * gm.w + bt.w;
    if (outf) {
        float4 y; y.x = y0; y.y = y1; y.z = y2; y.w = y3;
        ((float4*)(outf + (size_t)row * 1024))[tid] = y;
    }
    if (outb) {
        ushort4 ub;
        ub.x = f2bfu(y0); ub.y = f2bfu(y1); ub.z = f2bfu(y2); ub.w = f2bfu(y3);
        ((ushort4*)outb)[row * 256 + tid] = ub;
    }
}

// ---------------- host ----------------
extern "C" void kernel_launch(void* const* d_in, const int* in_sizes, int n_in,
                              void* d_out, int out_size, void* d_ws, size_t ws_size,
                              hipStream_t stream)
{
    const float* x    = (const float*)d_in[0];
    const unsigned char* kpm = (const unsigned char*)d_in[1];
    const float* Wq = (const float*)d_in[2];
    const float* bq = (const float*)d_in[3];
    const float* Wk = (const float*)d_in[4];
    const float* bk = (const float*)d_in[5];
    const float* Wv = (const float*)d_in[6];
    const float* bv = (const float*)d_in[7];
    const float* Wo = (const float*)d_in[8];
    const float* bo = (const float*)d_in[9];
    const float* W1 = (const float*)d_in[10];
    const float* b1 = (const float*)d_in[11];
    const float* W2 = (const float*)d_in[12];
    const float* b2 = (const float*)d_in[13];
    const float* ln1g = (const float*)d_in[14];
    const float* ln1b = (const float*)d_in[15];
    const float* ln2g = (const float*)d_in[16];
    const float* ln2b = (const float*)d_in[17];
    float* out = (float*)d_out;

    char* ws = (char*)d_ws;
    const size_t SZ_ND2 = (size_t)8192 * 1024 * 2;
    size_t off = 0;
    __hip_bfloat16* xb  = (__hip_bfloat16*)(ws + off); off += SZ_ND2;
    __hip_bfloat16* wqb = (__hip_bfloat16*)(ws + off); off += (size_t)1024 * 1024 * 2;
    __hip_bfloat16* wkb = (__hip_bfloat16*)(ws + off); off += (size_t)1024 * 1024 * 2;
    __hip_bfloat16* wvb = (__hip_bfloat16*)(ws + off); off += (size_t)1024 * 1024 * 2;
    __hip_bfloat16* wob = (__hip_bfloat16*)(ws + off); off += (size_t)1024 * 1024 * 2;
    __hip_bfloat16* w1b = (__hip_bfloat16*)(ws + off); off += (size_t)4096 * 1024 * 2;
    __hip_bfloat16* w2b = (__hip_bfloat16*)(ws + off); off += (size_t)4096 * 1024 * 2;
    const size_t qkv0 = off;
    __hip_bfloat16* qbp = (__hip_bfloat16*)(ws + off); off += SZ_ND2;
    __hip_bfloat16* kbp = (__hip_bfloat16*)(ws + off); off += SZ_ND2;
    __hip_bfloat16* vtg = (__hip_bfloat16*)(ws + off); off += SZ_ND2;
    __hip_bfloat16* abp = (__hip_bfloat16*)(ws + off); off += SZ_ND2;
    __hip_bfloat16* hbp = (__hip_bfloat16*)(ws + qkv0);
    __hip_bfloat16* y1b = (__hip_bfloat16*)(ws + off); off += SZ_ND2;
    __hip_bfloat16* x1b = (__hip_bfloat16*)(ws + off); off += SZ_ND2;
    __hip_bfloat16* y2b = y1b;
    float* bqkv = (float*)(ws + off); off += 3072 * 4;

    cvt_all_kernel<<<20480, 256, 0, stream>>>(
        (const float4*)x,  (ushort4*)xb,
        (const float4*)Wq, (ushort4*)wqb,
        (const float4*)Wk, (ushort4*)wkb,
        (const float4*)Wv, (ushort4*)wvb,
        (const float4*)Wo, (ushort4*)wob,
        (const float4*)W1, (ushort4*)w1b,
        (const float4*)W2, (ushort4*)w2b);
    hipMemcpyAsync(bqkv,        bq, 4096, hipMemcpyDeviceToDevice, stream);
    hipMemcpyAsync(bqkv + 1024, bk, 4096, hipMemcpyDeviceToDevice, stream);
    hipMemcpyAsync(bqkv + 2048, bv, 4096, hipMemcpyDeviceToDevice, stream);

    const float qscale = 0.125f * 1.44269504088896f;

    // QKV: 128x256 2-phase kernel, grid 64x12 = 768 blocks = 3 full rounds
    gemm2p_w<EPI_QKV><<<dim3(64, 12), 512, 0, stream>>>(
        xb, wqb, bqkv, nullptr, qscale, qbp, kbp, vtg, 8192, 3072, 1024);

    attn_flash3<<<dim3(8, 64), 512, 0, stream>>>(qbp, kbp, vtg, kpm, abp);

    // proj: 128x256 2-phase kernel, grid 64x4 = 256 blocks = exactly 1/CU
    gemm2p_w<EPI_RES_OB><<<dim3(64, 4), 512, 0, stream>>>(
        abp, wob, bo, xb, 1.0f, y1b, nullptr, nullptr, 8192, 1024, 1024);
    ln_b_kernel<<<8192, 256, 0, stream>>>(y1b, ln1g, ln1b, nullptr, x1b);

    // FFN1 on the proven 8-phase 256^2 kernel (512 blocks = 2 full rounds)
    gemm8p<EPI_GELU><<<dim3(32, 16), 512, 0, stream>>>(
        x1b, w1b, b1, nullptr, 1.0f, hbp, 8192, 4096, 1024);
    // FFN2 on the 128x256 2-phase kernel (64x4 = 256 blocks = exactly 1/CU)
    gemm2p_w<EPI_RES_OB><<<dim3(64, 4), 512, 0, stream>>>(
        hbp, w2b, b2, x1b, 1.0f, y2b, nullptr, nullptr, 8192, 1024, 4096);
    ln_b_kernel<<<8192, 256, 0, stream>>>(y2b, ln2g, ln2b, out, nullptr);
}